// Round 9
// baseline (88.757 us; speedup 1.0000x reference)
//
#include <hip/hip_runtime.h>
#include <math.h>

#define NB   8
#define SEQ  2048
#define EMB  8
#define NH   4
#define NFF  2048
#define NTOK (NB*SEQ)          // 16384
#define LNEPS 1e-5f

typedef float v2f __attribute__((ext_vector_type(2)));

__device__ __forceinline__ float dot8(const float4& a, const float4& b,
                                      const float4& c, const float4& d) {
    return a.x*b.x + a.y*b.y + a.z*b.z + a.w*b.w
         + c.x*d.x + c.y*d.y + c.z*d.z + c.w*d.w;
}

// ---------------------------------------------------------------------------
// projH[(b*4+h)][s][2] = (x @ Wp^T) head-major, and W2T[f][e] = W2[e][f]
// ---------------------------------------------------------------------------
__global__ __launch_bounds__(128) void k_prep(const float* __restrict__ x,
                                              const float* __restrict__ Wp,
                                              const float* __restrict__ W2,
                                              float* __restrict__ projH,
                                              float* __restrict__ w2t) {
    int t = blockIdx.x * 128 + threadIdx.x;
    if (t < NTOK) {
        int b = t >> 11, s = t & (SEQ - 1);
        const float4* xr = (const float4*)(x + (size_t)t * EMB);
        float4 xa = xr[0], xb = xr[1];
        float o[8];
#pragma unroll
        for (int e = 0; e < 8; ++e) {
            const float4* wr = (const float4*)(Wp + e * EMB);
            o[e] = dot8(xa, wr[0], xb, wr[1]);
        }
#pragma unroll
        for (int h = 0; h < 4; ++h) {
            *(float2*)(projH + ((size_t)(b * 4 + h) * SEQ + s) * 2) =
                make_float2(o[2 * h], o[2 * h + 1]);
        }
    }
    if (t < NFF) {
        float o[8];
#pragma unroll
        for (int e = 0; e < 8; ++e) o[e] = W2[e * NFF + t];
        float4* wr = (float4*)(w2t + (size_t)t * EMB);
        wr[0] = make_float4(o[0], o[1], o[2], o[3]);
        wr[1] = make_float4(o[4], o[5], o[6], o[7]);
    }
}

// ---------------------------------------------------------------------------
// attention v3 (unchanged from R8 — best measured, A3 ~= 24 us).
// ---------------------------------------------------------------------------
#define QCA 64
__global__ __launch_bounds__(256) void k_attn(const float* __restrict__ projH,
                                              float* __restrict__ ctx) {
    __shared__ float Kx[SEQ];               // 8 KB  (pre-scaled by 1/sqrt2)
    __shared__ float Ky[SEQ];               // 8 KB
    __shared__ float red[3][8][QCA];        // 6 KB

    int bid = blockIdx.x;
    int qc  = bid & 31;                     // 32 query chunks of 64
    int bh  = bid >> 5;                     // (b*4+h)

    const float SC = 0.70710678118654752f;  // 1/sqrt(DK)
    const float4* gsr = (const float4*)(projH + (size_t)bh * SEQ * 2);
#pragma unroll
    for (int ii = 0; ii < 4; ++ii) {
        int i = threadIdx.x + 256 * ii;
        float4 v = gsr[i];                  // keys 2i,2i+1: (x0,y0,x1,y1)
        *(float2*)&Kx[2 * i] = make_float2(v.x * SC, v.z * SC);
        *(float2*)&Ky[2 * i] = make_float2(v.y * SC, v.w * SC);
    }
    __syncthreads();

    int qg  = threadIdx.x & 31;             // 32 query groups of 2
    int sub = threadIdx.x >> 5;             // 8 key subranges of 256

    const float SQ2 = 1.41421356237309505f;
    int q0 = qc * QCA + qg * 2;
    float qxa = Kx[q0] * SQ2,     qya = Ky[q0] * SQ2;
    float qxb = Kx[q0 + 1] * SQ2, qyb = Ky[q0 + 1] * SQ2;
    v2f qx2a = {qxa, qxa}, qy2a = {qya, qya};
    v2f qx2b = {qxb, qxb}, qy2b = {qyb, qyb};

    v2f lA = {0.f, 0.f}, axA = {0.f, 0.f}, ayA = {0.f, 0.f};
    v2f lB = {0.f, 0.f}, axB = {0.f, 0.f}, ayB = {0.f, 0.f};

    const float4* Kx4 = (const float4*)Kx;
    const float4* Ky4 = (const float4*)Ky;
    int j04 = sub * 64;                     // 256 keys = 64 float4
#pragma unroll 2
    for (int jj = 0; jj < 64; ++jj) {
        float4 kx = Kx4[j04 + jj];          // broadcast reads: no conflicts
        float4 ky = Ky4[j04 + jj];
        v2f k0 = {kx.x, kx.y}, k1 = {kx.z, kx.w};
        v2f m0 = {ky.x, ky.y}, m1 = {ky.z, ky.w};

        v2f s0a = qx2a * k0 + qy2a * m0;
        v2f s1a = qx2a * k1 + qy2a * m1;
        v2f s0b = qx2b * k0 + qy2b * m0;
        v2f s1b = qx2b * k1 + qy2b * m1;

        v2f p0a, p1a, p0b, p1b;
        p0a.x = __expf(s0a.x); p0a.y = __expf(s0a.y);
        p1a.x = __expf(s1a.x); p1a.y = __expf(s1a.y);
        p0b.x = __expf(s0b.x); p0b.y = __expf(s0b.y);
        p1b.x = __expf(s1b.x); p1b.y = __expf(s1b.y);

        lA  += p0a;            lB  += p0b;
        axA += p0a * k0;       axB += p0b * k0;
        ayA += p0a * m0;       ayB += p0b * m0;
        lA  += p1a;            lB  += p1b;
        axA += p1a * k1;       axB += p1b * k1;
        ayA += p1a * m1;       ayB += p1b * m1;
    }
    red[0][sub][qg * 2]     = lA.x + lA.y;
    red[1][sub][qg * 2]     = axA.x + axA.y;
    red[2][sub][qg * 2]     = ayA.x + ayA.y;
    red[0][sub][qg * 2 + 1] = lB.x + lB.y;
    red[1][sub][qg * 2 + 1] = axB.x + axB.y;
    red[2][sub][qg * 2 + 1] = ayB.x + ayB.y;
    __syncthreads();

    if (threadIdx.x < QCA) {
        float L = 0.f, A0 = 0.f, A1 = 0.f;
#pragma unroll
        for (int s = 0; s < 8; ++s) {
            L  += red[0][s][threadIdx.x];
            A0 += red[1][s][threadIdx.x];
            A1 += red[2][s][threadIdx.x];
        }
        float inv = SQ2 / L;                // undo the 1/sqrt2 on staged k
        int b = bh >> 2, h = bh & 3;
        int qglob = qc * QCA + threadIdx.x;
        *(float2*)(ctx + ((size_t)b * SEQ + qglob) * EMB + 2 * h) =
            make_float2(A0 * inv, A1 * inv);
    }
}

// ---------------------------------------------------------------------------
// FUSED post+FFN v4.  512 threads, TB=32 tokens/block, grid=512.
// CONTIGUOUS-F FIX: wave w handles f rows [w*256, w*256+256); per iter i the
// wave's 8 sub-groups (sw = lane bits 3-5) read 8 CONSECUTIVE rows
// f = w*256 + i*8 + sw  ->  each W load instr touches 256B contiguous
// (2 cache lines) instead of 8 lines 1KB apart.  tg=tid&7: 4 tokens/thread,
// 8-lane broadcast per row (R2/R7-proven).  In-wave shfl reduce over sw,
// cross-wave LDS reduce, LN2 via 8-lane shuffles.
// ---------------------------------------------------------------------------
#define TB3  32                 // tokens per block
#define FCH3 32                 // f rows per thread
__global__ __launch_bounds__(512) void k_ffn3(const float* __restrict__ ctx,
                                              const float* __restrict__ x,
                                              const float* __restrict__ Wo,
                                              const float* __restrict__ g1,
                                              const float* __restrict__ b1,
                                              const float* __restrict__ W1,
                                              const float* __restrict__ bb1,
                                              const float* __restrict__ w2t,
                                              const float* __restrict__ bb2,
                                              const float* __restrict__ g2,
                                              const float* __restrict__ b2,
                                              float* __restrict__ out) {
    __shared__ float q_lds[TB3][8];         // 1 KB
    __shared__ float x1_lds[TB3][8];        // 1 KB
    __shared__ float red[8][TB3][8];        // 8 KB: per-wave partials

    int tid = threadIdx.x;

    // ---- prologue: post-attention for this block's 32 tokens (256 lanes) ----
    if (tid < TB3 * 8) {
        int tl = tid >> 3, e = tid & 7;
        int tok = blockIdx.x * TB3 + tl;
        const float4* cr = (const float4*)(ctx + (size_t)tok * EMB);
        float4 ca = cr[0], cb = cr[1];      // broadcast across the 8 lanes
        const float4* wr = (const float4*)(Wo + e * EMB);
        float ao = dot8(ca, wr[0], cb, wr[1]);
        float y = x[(size_t)tok * EMB + e] + ao;

        float s8 = y;
        s8 += __shfl_xor(s8, 1);
        s8 += __shfl_xor(s8, 2);
        s8 += __shfl_xor(s8, 4);
        float mu = s8 * 0.125f;
        float d  = y - mu;
        float vs = d * d;
        vs += __shfl_xor(vs, 1);
        vs += __shfl_xor(vs, 2);
        vs += __shfl_xor(vs, 4);
        float r = rsqrtf(vs * 0.125f + LNEPS);
        float v = d * r * g1[e] + b1[e];
        x1_lds[tl][e] = v;

        float p = __cosf(v);
        float t1 = __shfl_up(p, 1, 8); p = (e >= 1) ? p * t1 : p;
        float t2 = __shfl_up(p, 2, 8); p = (e >= 2) ? p * t2 : p;
        float t4 = __shfl_up(p, 4, 8); p = (e >= 4) ? p * t4 : p;
        q_lds[tl][e] = p;
    }
    __syncthreads();

    // ---- main FFN loop: 4 tokens x 32 consecutive-f rows per wave-slot ----
    int tg = tid & 7;                       // 8 token groups x 4 tokens
    int sw = (tid >> 3) & 7;                // sub-in-wave (lane bits 3-5)
    int wv = tid >> 6;                      // wave 0..7
    int tl0 = tg * 4;

    float4 qa[4], qb[4];
#pragma unroll
    for (int k = 0; k < 4; ++k) {
        qa[k] = *(const float4*)&q_lds[tl0 + k][0];   // 8-lane broadcast
        qb[k] = *(const float4*)&q_lds[tl0 + k][4];
    }

    float acc[4][8];
#pragma unroll
    for (int k = 0; k < 4; ++k)
#pragma unroll
        for (int e = 0; e < 8; ++e) acc[k][e] = 0.f;

    int fbase = wv * 256 + sw;              // wave covers [wv*256, wv*256+256)
#pragma unroll 2
    for (int i = 0; i < FCH3; ++i) {
        int f = fbase + i * 8;              // wave instr: rows f..f+7 contiguous
        const float4* w1r = (const float4*)(W1 + (size_t)f * EMB);
        float4 wa = w1r[0], wb = w1r[1];
        float bias = bb1[f];
        const float4* w2r = (const float4*)(w2t + (size_t)f * EMB);
        float4 va = w2r[0], vb = w2r[1];
#pragma unroll
        for (int k = 0; k < 4; ++k) {
            float hv = fmaxf(dot8(qa[k], wa, qb[k], wb) + bias, 0.f);
            acc[k][0] = fmaf(hv, va.x, acc[k][0]);
            acc[k][1] = fmaf(hv, va.y, acc[k][1]);
            acc[k][2] = fmaf(hv, va.z, acc[k][2]);
            acc[k][3] = fmaf(hv, va.w, acc[k][3]);
            acc[k][4] = fmaf(hv, vb.x, acc[k][4]);
            acc[k][5] = fmaf(hv, vb.y, acc[k][5]);
            acc[k][6] = fmaf(hv, vb.z, acc[k][6]);
            acc[k][7] = fmaf(hv, vb.w, acc[k][7]);
        }
    }

    // in-wave reduce across the 8 sw groups (lane bits 3..5)
#pragma unroll
    for (int k = 0; k < 4; ++k)
#pragma unroll
        for (int e = 0; e < 8; ++e) {
            float v = acc[k][e];
            v += __shfl_xor(v, 8);
            v += __shfl_xor(v, 16);
            v += __shfl_xor(v, 32);
            acc[k][e] = v;
        }
    if (sw == 0) {                          // one sub-group per wave writes
#pragma unroll
        for (int k = 0; k < 4; ++k) {
            float4* d0 = (float4*)&red[wv][tl0 + k][0];
            d0[0] = make_float4(acc[k][0], acc[k][1], acc[k][2], acc[k][3]);
            d0[1] = make_float4(acc[k][4], acc[k][5], acc[k][6], acc[k][7]);
        }
    }
    __syncthreads();

    // ---- cross-wave reduce + LN2 (256 lanes = 32 tok x 8 e) ----
    if (tid < TB3 * 8) {
        int rtok = tid >> 3, re = tid & 7;
        float v = 0.f;
#pragma unroll
        for (int w = 0; w < 8; ++w) v += red[w][rtok][re];
        int tok = blockIdx.x * TB3 + rtok;
        v += bb2[re] + x1_lds[rtok][re];

        float s8 = v;
        s8 += __shfl_xor(s8, 1);
        s8 += __shfl_xor(s8, 2);
        s8 += __shfl_xor(s8, 4);
        float mu = s8 * 0.125f;
        float d  = v - mu;
        float vs = d * d;
        vs += __shfl_xor(vs, 1);
        vs += __shfl_xor(vs, 2);
        vs += __shfl_xor(vs, 4);
        float r = rsqrtf(vs * 0.125f + LNEPS);
        out[(size_t)tok * EMB + re] = d * r * g2[re] + b2[re];
    }
}

// ---------------------------------------------------------------------------
extern "C" void kernel_launch(void* const* d_in, const int* in_sizes, int n_in,
                              void* d_out, int out_size, void* d_ws, size_t ws_size,
                              hipStream_t stream) {
    const float* x   = (const float*)d_in[0];
    const float* Wp  = (const float*)d_in[1];
    const float* Wo  = (const float*)d_in[2];
    const float* g1  = (const float*)d_in[3];
    const float* b1  = (const float*)d_in[4];
    const float* W1  = (const float*)d_in[5];
    const float* bb1 = (const float*)d_in[6];
    const float* W2  = (const float*)d_in[7];
    const float* bb2 = (const float*)d_in[8];
    const float* g2  = (const float*)d_in[9];
    const float* b2  = (const float*)d_in[10];
    float* out = (float*)d_out;

    float* ws    = (float*)d_ws;
    float* projH = ws;                // 131072 f32 (head-major)
    float* ctx   = ws + 131072;       // 131072 f32
    float* w2t   = ws + 262144;       // 16384 f32

    hipLaunchKernelGGL(k_prep, dim3(NTOK / 128), dim3(128), 0, stream,
                       x, Wp, W2, projH, w2t);
    hipLaunchKernelGGL(k_attn, dim3((NB * NH) * (SEQ / QCA)), dim3(256), 0, stream,
                       projH, ctx);
    // ATTRIBUTION PROBE: k_ffn3 launched twice (idempotent — reads ctx/x,
    // writes out deterministically).  P+A3 ~= 28.4 us is pinned from R6-R8,
    // so dur = 28.4 + 2*F_new solves F_new AND measures the contiguous-f fix.
    // Drop the duplicate next round.
    hipLaunchKernelGGL(k_ffn3, dim3(NTOK / TB3), dim3(512), 0, stream,
                       ctx, x, Wo, g1, b1, W1, bb1, w2t, bb2, g2, b2, out);
    hipLaunchKernelGGL(k_ffn3, dim3(NTOK / TB3), dim3(512), 0, stream,
                       ctx, x, Wo, g1, b1, W1, bb1, w2t, bb2, g2, b2, out);
}

// Round 10
// 58.144 us; speedup vs baseline: 1.5265x; 1.5265x over previous
//
#include <hip/hip_runtime.h>
#include <math.h>

#define NB   8
#define SEQ  2048
#define EMB  8
#define NH   4
#define NFF  2048
#define NTOK (NB*SEQ)          // 16384
#define LNEPS 1e-5f

typedef float v2f __attribute__((ext_vector_type(2)));

__device__ __forceinline__ float dot8(const float4& a, const float4& b,
                                      const float4& c, const float4& d) {
    return a.x*b.x + a.y*b.y + a.z*b.z + a.w*b.w
         + c.x*d.x + c.y*d.y + c.z*d.z + c.w*d.w;
}

// ---------------------------------------------------------------------------
// projH[(b*4+h)][s][2] = (x @ Wp^T) head-major, and W2T[f][e] = W2[e][f]
// ---------------------------------------------------------------------------
__global__ __launch_bounds__(128) void k_prep(const float* __restrict__ x,
                                              const float* __restrict__ Wp,
                                              const float* __restrict__ W2,
                                              float* __restrict__ projH,
                                              float* __restrict__ w2t) {
    int t = blockIdx.x * 128 + threadIdx.x;
    if (t < NTOK) {
        int b = t >> 11, s = t & (SEQ - 1);
        const float4* xr = (const float4*)(x + (size_t)t * EMB);
        float4 xa = xr[0], xb = xr[1];
        float o[8];
#pragma unroll
        for (int e = 0; e < 8; ++e) {
            const float4* wr = (const float4*)(Wp + e * EMB);
            o[e] = dot8(xa, wr[0], xb, wr[1]);
        }
#pragma unroll
        for (int h = 0; h < 4; ++h) {
            *(float2*)(projH + ((size_t)(b * 4 + h) * SEQ + s) * 2) =
                make_float2(o[2 * h], o[2 * h + 1]);
        }
    }
    if (t < NFF) {
        float o[8];
#pragma unroll
        for (int e = 0; e < 8; ++e) o[e] = W2[e * NFF + t];
        float4* wr = (float4*)(w2t + (size_t)t * EMB);
        wr[0] = make_float4(o[0], o[1], o[2], o[3]);
        wr[1] = make_float4(o[4], o[5], o[6], o[7]);
    }
}

// ---------------------------------------------------------------------------
// attention v3 (R8 pk version, unchanged — measured ~5 us).
// ---------------------------------------------------------------------------
#define QCA 64
__global__ __launch_bounds__(256) void k_attn(const float* __restrict__ projH,
                                              float* __restrict__ ctx) {
    __shared__ float Kx[SEQ];               // 8 KB  (pre-scaled by 1/sqrt2)
    __shared__ float Ky[SEQ];               // 8 KB
    __shared__ float red[3][8][QCA];        // 6 KB

    int bid = blockIdx.x;
    int qc  = bid & 31;                     // 32 query chunks of 64
    int bh  = bid >> 5;                     // (b*4+h)

    const float SC = 0.70710678118654752f;  // 1/sqrt(DK)
    const float4* gsr = (const float4*)(projH + (size_t)bh * SEQ * 2);
#pragma unroll
    for (int ii = 0; ii < 4; ++ii) {
        int i = threadIdx.x + 256 * ii;
        float4 v = gsr[i];                  // keys 2i,2i+1: (x0,y0,x1,y1)
        *(float2*)&Kx[2 * i] = make_float2(v.x * SC, v.z * SC);
        *(float2*)&Ky[2 * i] = make_float2(v.y * SC, v.w * SC);
    }
    __syncthreads();

    int qg  = threadIdx.x & 31;             // 32 query groups of 2
    int sub = threadIdx.x >> 5;             // 8 key subranges of 256

    const float SQ2 = 1.41421356237309505f;
    int q0 = qc * QCA + qg * 2;
    float qxa = Kx[q0] * SQ2,     qya = Ky[q0] * SQ2;
    float qxb = Kx[q0 + 1] * SQ2, qyb = Ky[q0 + 1] * SQ2;
    v2f qx2a = {qxa, qxa}, qy2a = {qya, qya};
    v2f qx2b = {qxb, qxb}, qy2b = {qyb, qyb};

    v2f lA = {0.f, 0.f}, axA = {0.f, 0.f}, ayA = {0.f, 0.f};
    v2f lB = {0.f, 0.f}, axB = {0.f, 0.f}, ayB = {0.f, 0.f};

    const float4* Kx4 = (const float4*)Kx;
    const float4* Ky4 = (const float4*)Ky;
    int j04 = sub * 64;                     // 256 keys = 64 float4
#pragma unroll 2
    for (int jj = 0; jj < 64; ++jj) {
        float4 kx = Kx4[j04 + jj];          // broadcast reads: no conflicts
        float4 ky = Ky4[j04 + jj];
        v2f k0 = {kx.x, kx.y}, k1 = {kx.z, kx.w};
        v2f m0 = {ky.x, ky.y}, m1 = {ky.z, ky.w};

        v2f s0a = qx2a * k0 + qy2a * m0;
        v2f s1a = qx2a * k1 + qy2a * m1;
        v2f s0b = qx2b * k0 + qy2b * m0;
        v2f s1b = qx2b * k1 + qy2b * m1;

        v2f p0a, p1a, p0b, p1b;
        p0a.x = __expf(s0a.x); p0a.y = __expf(s0a.y);
        p1a.x = __expf(s1a.x); p1a.y = __expf(s1a.y);
        p0b.x = __expf(s0b.x); p0b.y = __expf(s0b.y);
        p1b.x = __expf(s1b.x); p1b.y = __expf(s1b.y);

        lA  += p0a;            lB  += p0b;
        axA += p0a * k0;       axB += p0b * k0;
        ayA += p0a * m0;       ayB += p0b * m0;
        lA  += p1a;            lB  += p1b;
        axA += p1a * k1;       axB += p1b * k1;
        ayA += p1a * m1;       ayB += p1b * m1;
    }
    red[0][sub][qg * 2]     = lA.x + lA.y;
    red[1][sub][qg * 2]     = axA.x + axA.y;
    red[2][sub][qg * 2]     = ayA.x + ayA.y;
    red[0][sub][qg * 2 + 1] = lB.x + lB.y;
    red[1][sub][qg * 2 + 1] = axB.x + axB.y;
    red[2][sub][qg * 2 + 1] = ayB.x + ayB.y;
    __syncthreads();

    if (threadIdx.x < QCA) {
        float L = 0.f, A0 = 0.f, A1 = 0.f;
#pragma unroll
        for (int s = 0; s < 8; ++s) {
            L  += red[0][s][threadIdx.x];
            A0 += red[1][s][threadIdx.x];
            A1 += red[2][s][threadIdx.x];
        }
        float inv = SQ2 / L;                // undo the 1/sqrt2 on staged k
        int b = bh >> 2, h = bh & 3;
        int qglob = qc * QCA + threadIdx.x;
        *(float2*)(ctx + ((size_t)b * SEQ + qglob) * EMB + 2 * h) =
            make_float2(A0 * inv, A1 * inv);
    }
}

// ---------------------------------------------------------------------------
// FUSED post+FFN v5.  512 threads, TB=32 tokens/block, grid=512.
// R7-PROVEN f mapping: sub = tid>>3, f = sub*32 + i — each thread WALKS
// consecutive 32B rows, so iters i..i+3 hit the same 128B line (L1 reuse;
// this beat the contiguous-per-instr mapping 28.9 vs 41.1 us in R9).
// unroll 4 -> ~20 loads in flight to cover residual L2 latency.
// tg=tid&7: 4 tokens/thread, 8-lane broadcast per row.  In-wave shfl
// reduce over lane bits 3-5, cross-wave LDS reduce, LN2 via 8-lane shfl.
// ---------------------------------------------------------------------------
#define TB3  32                 // tokens per block
#define FCH3 32                 // f rows per thread
__global__ __launch_bounds__(512) void k_ffn3(const float* __restrict__ ctx,
                                              const float* __restrict__ x,
                                              const float* __restrict__ Wo,
                                              const float* __restrict__ g1,
                                              const float* __restrict__ b1,
                                              const float* __restrict__ W1,
                                              const float* __restrict__ bb1,
                                              const float* __restrict__ w2t,
                                              const float* __restrict__ bb2,
                                              const float* __restrict__ g2,
                                              const float* __restrict__ b2,
                                              float* __restrict__ out) {
    __shared__ float q_lds[TB3][8];         // 1 KB
    __shared__ float x1_lds[TB3][8];        // 1 KB
    __shared__ float red[8][TB3][8];        // 8 KB: per-wave partials

    int tid = threadIdx.x;

    // ---- prologue: post-attention for this block's 32 tokens (256 lanes) ----
    if (tid < TB3 * 8) {
        int tl = tid >> 3, e = tid & 7;
        int tok = blockIdx.x * TB3 + tl;
        const float4* cr = (const float4*)(ctx + (size_t)tok * EMB);
        float4 ca = cr[0], cb = cr[1];      // broadcast across the 8 lanes
        const float4* wr = (const float4*)(Wo + e * EMB);
        float ao = dot8(ca, wr[0], cb, wr[1]);
        float y = x[(size_t)tok * EMB + e] + ao;

        float s8 = y;
        s8 += __shfl_xor(s8, 1);
        s8 += __shfl_xor(s8, 2);
        s8 += __shfl_xor(s8, 4);
        float mu = s8 * 0.125f;
        float d  = y - mu;
        float vs = d * d;
        vs += __shfl_xor(vs, 1);
        vs += __shfl_xor(vs, 2);
        vs += __shfl_xor(vs, 4);
        float r = rsqrtf(vs * 0.125f + LNEPS);
        float v = d * r * g1[e] + b1[e];
        x1_lds[tl][e] = v;

        float p = __cosf(v);
        float t1 = __shfl_up(p, 1, 8); p = (e >= 1) ? p * t1 : p;
        float t2 = __shfl_up(p, 2, 8); p = (e >= 2) ? p * t2 : p;
        float t4 = __shfl_up(p, 4, 8); p = (e >= 4) ? p * t4 : p;
        q_lds[tl][e] = p;
    }
    __syncthreads();

    // ---- main FFN loop: 4 tokens x 32 sequential f rows per thread ----
    int tg  = tid & 7;                      // 8 token groups x 4 tokens
    int sub = tid >> 3;                     // 64 f-subranges
    int tl0 = tg * 4;

    float4 qa[4], qb[4];
#pragma unroll
    for (int k = 0; k < 4; ++k) {
        qa[k] = *(const float4*)&q_lds[tl0 + k][0];   // 8-lane broadcast
        qb[k] = *(const float4*)&q_lds[tl0 + k][4];
    }

    float acc[4][8];
#pragma unroll
    for (int k = 0; k < 4; ++k)
#pragma unroll
        for (int e = 0; e < 8; ++e) acc[k][e] = 0.f;

    int f0 = sub * FCH3;
#pragma unroll 4
    for (int i = 0; i < FCH3; ++i) {
        int f = f0 + i;                     // walks consecutive rows: L1 reuse
        const float4* w1r = (const float4*)(W1 + (size_t)f * EMB);
        float4 wa = w1r[0], wb = w1r[1];
        float bias = bb1[f];
        const float4* w2r = (const float4*)(w2t + (size_t)f * EMB);
        float4 va = w2r[0], vb = w2r[1];
#pragma unroll
        for (int k = 0; k < 4; ++k) {
            float hv = fmaxf(dot8(qa[k], wa, qb[k], wb) + bias, 0.f);
            acc[k][0] = fmaf(hv, va.x, acc[k][0]);
            acc[k][1] = fmaf(hv, va.y, acc[k][1]);
            acc[k][2] = fmaf(hv, va.z, acc[k][2]);
            acc[k][3] = fmaf(hv, va.w, acc[k][3]);
            acc[k][4] = fmaf(hv, vb.x, acc[k][4]);
            acc[k][5] = fmaf(hv, vb.y, acc[k][5]);
            acc[k][6] = fmaf(hv, vb.z, acc[k][6]);
            acc[k][7] = fmaf(hv, vb.w, acc[k][7]);
        }
    }

    // in-wave reduce across the 8 sub groups (lane bits 3..5)
#pragma unroll
    for (int k = 0; k < 4; ++k)
#pragma unroll
        for (int e = 0; e < 8; ++e) {
            float v = acc[k][e];
            v += __shfl_xor(v, 8);
            v += __shfl_xor(v, 16);
            v += __shfl_xor(v, 32);
            acc[k][e] = v;
        }
    int wv = tid >> 6;                      // wave 0..7
    if (((tid >> 3) & 7) == 0) {            // one sub-group per wave writes
#pragma unroll
        for (int k = 0; k < 4; ++k) {
            float4* d0 = (float4*)&red[wv][tl0 + k][0];
            d0[0] = make_float4(acc[k][0], acc[k][1], acc[k][2], acc[k][3]);
            d0[1] = make_float4(acc[k][4], acc[k][5], acc[k][6], acc[k][7]);
        }
    }
    __syncthreads();

    // ---- cross-wave reduce + LN2 (256 lanes = 32 tok x 8 e) ----
    if (tid < TB3 * 8) {
        int rtok = tid >> 3, re = tid & 7;
        float v = 0.f;
#pragma unroll
        for (int w = 0; w < 8; ++w) v += red[w][rtok][re];
        int tok = blockIdx.x * TB3 + rtok;
        v += bb2[re] + x1_lds[rtok][re];

        float s8 = v;
        s8 += __shfl_xor(s8, 1);
        s8 += __shfl_xor(s8, 2);
        s8 += __shfl_xor(s8, 4);
        float mu = s8 * 0.125f;
        float d  = v - mu;
        float vs = d * d;
        vs += __shfl_xor(vs, 1);
        vs += __shfl_xor(vs, 2);
        vs += __shfl_xor(vs, 4);
        float r = rsqrtf(vs * 0.125f + LNEPS);
        out[(size_t)tok * EMB + re] = d * r * g2[re] + b2[re];
    }
}

// ---------------------------------------------------------------------------
extern "C" void kernel_launch(void* const* d_in, const int* in_sizes, int n_in,
                              void* d_out, int out_size, void* d_ws, size_t ws_size,
                              hipStream_t stream) {
    const float* x   = (const float*)d_in[0];
    const float* Wp  = (const float*)d_in[1];
    const float* Wo  = (const float*)d_in[2];
    const float* g1  = (const float*)d_in[3];
    const float* b1  = (const float*)d_in[4];
    const float* W1  = (const float*)d_in[5];
    const float* bb1 = (const float*)d_in[6];
    const float* W2  = (const float*)d_in[7];
    const float* bb2 = (const float*)d_in[8];
    const float* g2  = (const float*)d_in[9];
    const float* b2  = (const float*)d_in[10];
    float* out = (float*)d_out;

    float* ws    = (float*)d_ws;
    float* projH = ws;                // 131072 f32 (head-major)
    float* ctx   = ws + 131072;       // 131072 f32
    float* w2t   = ws + 262144;       // 16384 f32

    hipLaunchKernelGGL(k_prep, dim3(NTOK / 128), dim3(128), 0, stream,
                       x, Wp, W2, projH, w2t);
    hipLaunchKernelGGL(k_attn, dim3((NB * NH) * (SEQ / QCA)), dim3(256), 0, stream,
                       projH, ctx);
    hipLaunchKernelGGL(k_ffn3, dim3(NTOK / TB3), dim3(512), 0, stream,
                       ctx, x, Wo, g1, b1, W1, bb1, w2t, bb2, g2, b2, out);
}